// Round 1
// baseline (9998.684 us; speedup 1.0000x reference)
//
#include <hip/hip_runtime.h>
#include <math.h>

#define BB 2
#define SS 2048
#define HH 768
#define NHH 12
#define LL 4
#define DD 64
#define WW 128
#define GG 16
#define PP 128
#define NLL 3
#define FF 3072

// ---------------------------------------------------------------------------
// Embedding gather: x[row,:] = emb[ids[row],:]
__global__ __launch_bounds__(256) void embed_kernel(const int* __restrict__ ids,
    const float* __restrict__ emb, float* __restrict__ x)
{
    int row = blockIdx.x;
    int id = ids[row];
    const float* e = emb + (size_t)id * HH;
    float* xp = x + (size_t)row * HH;
    for (int i = threadIdx.x; i < HH; i += 256) xp[i] = e[i];
}

// ---------------------------------------------------------------------------
// C[M,N] = epi(A[M,K] @ Bw[K,N] + bias[N])
// epi: 0 none | 1 *scale | 2 +res | 3 gelu(tanh approx)
// M,N multiples of 64; K multiple of 16.
__global__ __launch_bounds__(256) void gemm_kernel(const float* __restrict__ A,
    const float* __restrict__ Bw, const float* __restrict__ bias,
    const float* __restrict__ res, float* __restrict__ Cmat,
    int M, int N, int K, int epi, float scale)
{
    __shared__ float As[64][17];
    __shared__ float Bs[16][65];
    int tid = threadIdx.x;
    int tx = tid & 15, ty = tid >> 4;
    int tileM = blockIdx.y * 64, tileN = blockIdx.x * 64;
    float acc[4][4] = {};
    for (int k0 = 0; k0 < K; k0 += 16) {
        #pragma unroll
        for (int i = 0; i < 4; i++) {
            int e = tid + i * 256;
            int ar = e >> 4, ac = e & 15;
            As[ar][ac] = A[(size_t)(tileM + ar) * K + k0 + ac];
        }
        #pragma unroll
        for (int i = 0; i < 4; i++) {
            int e = tid + i * 256;
            int br = e >> 6, bc = e & 63;
            Bs[br][bc] = Bw[(size_t)(k0 + br) * N + tileN + bc];
        }
        __syncthreads();
        #pragma unroll
        for (int kk = 0; kk < 16; kk++) {
            float a[4], b[4];
            #pragma unroll
            for (int i = 0; i < 4; i++) a[i] = As[ty * 4 + i][kk];
            #pragma unroll
            for (int j = 0; j < 4; j++) b[j] = Bs[kk][tx * 4 + j];
            #pragma unroll
            for (int i = 0; i < 4; i++)
                #pragma unroll
                for (int j = 0; j < 4; j++) acc[i][j] += a[i] * b[j];
        }
        __syncthreads();
    }
    #pragma unroll
    for (int i = 0; i < 4; i++) {
        int r = tileM + ty * 4 + i;
        #pragma unroll
        for (int j = 0; j < 4; j++) {
            int c = tileN + tx * 4 + j;
            float v = acc[i][j] + bias[c];
            if (epi == 1) v *= scale;
            else if (epi == 2) v += res[(size_t)r * N + c];
            else if (epi == 3) {
                float xg = v;
                float t = 0.7978845608028654f * (xg + 0.044715f * xg * xg * xg);
                v = 0.5f * xg * (1.0f + tanhf(t));
            }
            Cmat[(size_t)r * N + c] = v;
        }
    }
}

// ---------------------------------------------------------------------------
// LayerNorm over last dim (H) per row. Safe for in==out.
__global__ __launch_bounds__(256) void ln_kernel(const float* __restrict__ in,
    const float* __restrict__ g, const float* __restrict__ b, float* __restrict__ out)
{
    int row = blockIdx.x;
    __shared__ float red[256];
    const float* x = in + (size_t)row * HH;
    int tid = threadIdx.x;
    float s = 0.f;
    for (int i = tid; i < HH; i += 256) s += x[i];
    red[tid] = s; __syncthreads();
    for (int st = 128; st > 0; st >>= 1) { if (tid < st) red[tid] += red[tid + st]; __syncthreads(); }
    float mean = red[0] / HH;
    __syncthreads();
    float vs = 0.f;
    for (int i = tid; i < HH; i += 256) { float d = x[i] - mean; vs += d * d; }
    red[tid] = vs; __syncthreads();
    for (int st = 128; st > 0; st >>= 1) { if (tid < st) red[tid] += red[tid + st]; __syncthreads(); }
    float rstd = rsqrtf(red[0] / HH + 1e-5f);
    __syncthreads();
    for (int i = tid; i < HH; i += 256)
        out[(size_t)row * HH + i] = (x[i] - mean) * rstd * g[i] + b[i];
}

// ---------------------------------------------------------------------------
// Band + global-key attention. One thread per query row.
// Effective key set for query s: {0..G-1} ∪ [max(G, s-W), min(S-1, s+W)].
// q pre-scaled by 1/sqrt(D). Layouts: q,k,v,o are (B,S,NH,D) row-major.
__global__ __launch_bounds__(128) void band_attn_kernel(const float* __restrict__ q,
    const float* __restrict__ k, const float* __restrict__ v, float* __restrict__ o)
{
    int h = blockIdx.x, n = blockIdx.y, b = blockIdx.z;
    int s = n * 128 + threadIdx.x;
    const float* qp = q + (((size_t)b * SS + s) * NHH + h) * DD;
    float qr[DD];
    #pragma unroll
    for (int d = 0; d < DD; d++) qr[d] = qp[d];
    float m = -INFINITY, l = 0.f;
    float oacc[DD] = {};
    int lo = s - WW; if (lo < GG) lo = GG;
    int hi = s + WW; if (hi > SS - 1) hi = SS - 1;
    for (int phase = 0; phase < 2; phase++) {
        int a0 = (phase == 0) ? 0 : lo;
        int a1 = (phase == 0) ? (GG - 1) : hi;
        for (int kpos = a0; kpos <= a1; kpos++) {
            const float* kp = k + (((size_t)b * SS + kpos) * NHH + h) * DD;
            float sc = 0.f;
            #pragma unroll
            for (int d = 0; d < DD; d++) sc += qr[d] * kp[d];
            float mn = fmaxf(m, sc);
            float corr = __expf(m - mn);
            float p = __expf(sc - mn);
            l = l * corr + p;
            const float* vp = v + (((size_t)b * SS + kpos) * NHH + h) * DD;
            #pragma unroll
            for (int d = 0; d < DD; d++) oacc[d] = oacc[d] * corr + p * vp[d];
            m = mn;
        }
    }
    float inv = 1.f / l;
    float* op = o + (((size_t)b * SS + s) * NHH + h) * DD;
    #pragma unroll
    for (int d = 0; d < DD; d++) op[d] = oacc[d] * inv;
}

// ---------------------------------------------------------------------------
// Global-query rows (s < G): full softmax attention over all S keys.
// Overwrites o rows [0, G).
__global__ __launch_bounds__(256) void global_attn_kernel(const float* __restrict__ q,
    const float* __restrict__ k, const float* __restrict__ v, float* __restrict__ o)
{
    int g = blockIdx.x, h = blockIdx.y, b = blockIdx.z;
    __shared__ float sc[SS];
    __shared__ float qs[DD];
    __shared__ float red[256];
    int tid = threadIdx.x;
    if (tid < DD) qs[tid] = q[(((size_t)b * SS + g) * NHH + h) * DD + tid];
    __syncthreads();
    for (int s0 = tid; s0 < SS; s0 += 256) {
        const float* kp = k + (((size_t)b * SS + s0) * NHH + h) * DD;
        float d0 = 0.f;
        #pragma unroll
        for (int d = 0; d < DD; d++) d0 += qs[d] * kp[d];
        sc[s0] = d0;
    }
    __syncthreads();
    float mx = -INFINITY;
    for (int s0 = tid; s0 < SS; s0 += 256) mx = fmaxf(mx, sc[s0]);
    red[tid] = mx; __syncthreads();
    for (int st = 128; st > 0; st >>= 1) { if (tid < st) red[tid] = fmaxf(red[tid], red[tid + st]); __syncthreads(); }
    mx = red[0]; __syncthreads();
    float sum = 0.f;
    for (int s0 = tid; s0 < SS; s0 += 256) { float p = __expf(sc[s0] - mx); sc[s0] = p; sum += p; }
    red[tid] = sum; __syncthreads();
    for (int st = 128; st > 0; st >>= 1) { if (tid < st) red[tid] += red[tid + st]; __syncthreads(); }
    float inv = 1.f / red[0];
    __syncthreads();
    int d = tid & 63, grp = tid >> 6;
    float acc = 0.f;
    for (int s0 = grp; s0 < SS; s0 += 4)
        acc += sc[s0] * v[(((size_t)b * SS + s0) * NHH + h) * DD + d];
    red[tid] = acc; __syncthreads();
    if (grp == 0) {
        float r = red[d] + red[64 + d] + red[128 + d] + red[192 + d];
        o[(((size_t)b * SS + g) * NHH + h) * DD + d] = r * inv;
    }
}

// ---------------------------------------------------------------------------
// Pair head: out[row,:] = concat(x[b,i,:], x[b,j,:]) @ Wh + bh
__global__ __launch_bounds__(256) void pair_head_kernel(const float* __restrict__ x,
    const int* __restrict__ pairs, const float* __restrict__ Wh,
    const float* __restrict__ bh, float* __restrict__ out)
{
    int row = blockIdx.x;
    int b = row / PP;
    int i = pairs[row * 2 + 0];
    int j = pairs[row * 2 + 1];
    const float* xi = x + ((size_t)b * SS + i) * HH;
    const float* xj = x + ((size_t)b * SS + j) * HH;
    float acc[NLL] = {};
    for (int e = threadIdx.x; e < 2 * HH; e += 256) {
        float val = (e < HH) ? xi[e] : xj[e - HH];
        #pragma unroll
        for (int c = 0; c < NLL; c++) acc[c] += val * Wh[e * NLL + c];
    }
    __shared__ float red[NLL * 256];
    #pragma unroll
    for (int c = 0; c < NLL; c++) red[c * 256 + threadIdx.x] = acc[c];
    __syncthreads();
    for (int st = 128; st > 0; st >>= 1) {
        if (threadIdx.x < st)
            #pragma unroll
            for (int c = 0; c < NLL; c++)
                red[c * 256 + threadIdx.x] += red[c * 256 + threadIdx.x + st];
        __syncthreads();
    }
    if (threadIdx.x < NLL) out[row * NLL + threadIdx.x] = red[threadIdx.x * 256] + bh[threadIdx.x];
}

// ---------------------------------------------------------------------------
extern "C" void kernel_launch(void* const* d_in, const int* in_sizes, int n_in,
                              void* d_out, int out_size, void* d_ws, size_t ws_size,
                              hipStream_t stream)
{
    const int*   input_ids    = (const int*)d_in[0];
    const int*   pair_indices = (const int*)d_in[1];
    const float* emb   = (const float*)d_in[2];
    const float* Wq    = (const float*)d_in[3];
    const float* bq    = (const float*)d_in[4];
    const float* Wk    = (const float*)d_in[5];
    const float* bk    = (const float*)d_in[6];
    const float* Wv    = (const float*)d_in[7];
    const float* bv    = (const float*)d_in[8];
    const float* Wo    = (const float*)d_in[9];
    const float* bo    = (const float*)d_in[10];
    const float* ln1_g = (const float*)d_in[11];
    const float* ln1_b = (const float*)d_in[12];
    const float* Wf1   = (const float*)d_in[13];
    const float* bf1   = (const float*)d_in[14];
    const float* Wf2   = (const float*)d_in[15];
    const float* bf2   = (const float*)d_in[16];
    const float* ln2_g = (const float*)d_in[17];
    const float* ln2_b = (const float*)d_in[18];
    const float* Wh    = (const float*)d_in[19];
    const float* bh    = (const float*)d_in[20];

    const size_t R = (size_t)BB * SS;   // 4096 rows
    float* ws = (float*)d_ws;
    float* x  = ws;              // R*H
    float* q  = x + R * HH;      // R*H
    float* k  = q + R * HH;      // R*H
    float* v  = k + R * HH;      // R*H
    float* o  = v + R * HH;      // R*H
    float* t1 = o + R * HH;      // R*H
    float* hb = q;               // R*FF aliases q..o (exactly 4*R*H floats)

    embed_kernel<<<dim3((int)R), 256, 0, stream>>>(input_ids, emb, x);

    dim3 gHH(HH / 64, (int)R / 64);
    dim3 gFF(FF / 64, (int)R / 64);
    for (int l = 0; l < LL; l++) {
        const float* lWq = Wq + (size_t)l * HH * HH;  const float* lbq = bq + (size_t)l * HH;
        const float* lWk = Wk + (size_t)l * HH * HH;  const float* lbk = bk + (size_t)l * HH;
        const float* lWv = Wv + (size_t)l * HH * HH;  const float* lbv = bv + (size_t)l * HH;
        const float* lWo = Wo + (size_t)l * HH * HH;  const float* lbo = bo + (size_t)l * HH;
        const float* lg1 = ln1_g + (size_t)l * HH;    const float* lb1 = ln1_b + (size_t)l * HH;
        const float* lWf1 = Wf1 + (size_t)l * HH * FF; const float* lbf1 = bf1 + (size_t)l * FF;
        const float* lWf2 = Wf2 + (size_t)l * FF * HH; const float* lbf2 = bf2 + (size_t)l * HH;
        const float* lg2 = ln2_g + (size_t)l * HH;    const float* lb2 = ln2_b + (size_t)l * HH;

        // q = (x@Wq + bq) * 1/sqrt(D);  k,v plain
        gemm_kernel<<<gHH, 256, 0, stream>>>(x, lWq, lbq, nullptr, q, (int)R, HH, HH, 1, 0.125f);
        gemm_kernel<<<gHH, 256, 0, stream>>>(x, lWk, lbk, nullptr, k, (int)R, HH, HH, 0, 0.f);
        gemm_kernel<<<gHH, 256, 0, stream>>>(x, lWv, lbv, nullptr, v, (int)R, HH, HH, 0, 0.f);

        band_attn_kernel<<<dim3(NHH, SS / 128, BB), 128, 0, stream>>>(q, k, v, o);
        global_attn_kernel<<<dim3(GG, NHH, BB), 256, 0, stream>>>(q, k, v, o);

        // t1 = o@Wo + bo + x ; x = LN(t1)
        gemm_kernel<<<gHH, 256, 0, stream>>>(o, lWo, lbo, x, t1, (int)R, HH, HH, 2, 0.f);
        ln_kernel<<<dim3((int)R), 256, 0, stream>>>(t1, lg1, lb1, x);

        // hb = gelu(x@Wf1 + bf1) ; t1 = hb@Wf2 + bf2 + x ; x = LN(t1)
        gemm_kernel<<<gFF, 256, 0, stream>>>(x, lWf1, lbf1, nullptr, hb, (int)R, FF, HH, 3, 0.f);
        gemm_kernel<<<gHH, 256, 0, stream>>>(hb, lWf2, lbf2, x, t1, (int)R, HH, FF, 2, 0.f);
        ln_kernel<<<dim3((int)R), 256, 0, stream>>>(t1, lg2, lb2, x);
    }

    pair_head_kernel<<<dim3(BB * PP), 256, 0, stream>>>(x, pair_indices, Wh, bh, (float*)d_out);
}

// Round 2
// 5998.727 us; speedup vs baseline: 1.6668x; 1.6668x over previous
//
#include <hip/hip_runtime.h>
#include <math.h>

#define BB 2
#define SS 2048
#define HH 768
#define NHH 12
#define LL 4
#define DD 64
#define WW 128
#define GG 16
#define PP 128
#define NLL 3
#define FF 3072

// ---------------------------------------------------------------------------
// Embedding gather: x[row,:] = emb[ids[row],:]
__global__ __launch_bounds__(256) void embed_kernel(const int* __restrict__ ids,
    const float* __restrict__ emb, float* __restrict__ x)
{
    int row = blockIdx.x;
    int id = ids[row];
    const float* e = emb + (size_t)id * HH;
    float* xp = x + (size_t)row * HH;
    for (int i = threadIdx.x; i < HH; i += 256) xp[i] = e[i];
}

// ---------------------------------------------------------------------------
// C[M,N] = epi(A[M,K] @ Bw[K,N] + bias[N])
// epi: 0 none | 1 *scale | 2 +res | 3 gelu(tanh approx)
__global__ __launch_bounds__(256) void gemm_kernel(const float* __restrict__ A,
    const float* __restrict__ Bw, const float* __restrict__ bias,
    const float* __restrict__ res, float* __restrict__ Cmat,
    int M, int N, int K, int epi, float scale)
{
    __shared__ float As[64][17];
    __shared__ float Bs[16][65];
    int tid = threadIdx.x;
    int tx = tid & 15, ty = tid >> 4;
    int tileM = blockIdx.y * 64, tileN = blockIdx.x * 64;
    float acc[4][4] = {};
    for (int k0 = 0; k0 < K; k0 += 16) {
        #pragma unroll
        for (int i = 0; i < 4; i++) {
            int e = tid + i * 256;
            int ar = e >> 4, ac = e & 15;
            As[ar][ac] = A[(size_t)(tileM + ar) * K + k0 + ac];
        }
        #pragma unroll
        for (int i = 0; i < 4; i++) {
            int e = tid + i * 256;
            int br = e >> 6, bc = e & 63;
            Bs[br][bc] = Bw[(size_t)(k0 + br) * N + tileN + bc];
        }
        __syncthreads();
        #pragma unroll
        for (int kk = 0; kk < 16; kk++) {
            float a[4], b[4];
            #pragma unroll
            for (int i = 0; i < 4; i++) a[i] = As[ty * 4 + i][kk];
            #pragma unroll
            for (int j = 0; j < 4; j++) b[j] = Bs[kk][tx * 4 + j];
            #pragma unroll
            for (int i = 0; i < 4; i++)
                #pragma unroll
                for (int j = 0; j < 4; j++) acc[i][j] += a[i] * b[j];
        }
        __syncthreads();
    }
    #pragma unroll
    for (int i = 0; i < 4; i++) {
        int r = tileM + ty * 4 + i;
        #pragma unroll
        for (int j = 0; j < 4; j++) {
            int c = tileN + tx * 4 + j;
            float v = acc[i][j] + bias[c];
            if (epi == 1) v *= scale;
            else if (epi == 2) v += res[(size_t)r * N + c];
            else if (epi == 3) {
                float xg = v;
                float t = 0.7978845608028654f * (xg + 0.044715f * xg * xg * xg);
                v = 0.5f * xg * (1.0f + tanhf(t));
            }
            Cmat[(size_t)r * N + c] = v;
        }
    }
}

// ---------------------------------------------------------------------------
// LayerNorm over last dim (H) per row. Safe for in==out.
__global__ __launch_bounds__(256) void ln_kernel(const float* __restrict__ in,
    const float* __restrict__ g, const float* __restrict__ b, float* __restrict__ out)
{
    int row = blockIdx.x;
    __shared__ float red[256];
    const float* x = in + (size_t)row * HH;
    int tid = threadIdx.x;
    float s = 0.f;
    for (int i = tid; i < HH; i += 256) s += x[i];
    red[tid] = s; __syncthreads();
    for (int st = 128; st > 0; st >>= 1) { if (tid < st) red[tid] += red[tid + st]; __syncthreads(); }
    float mean = red[0] / HH;
    __syncthreads();
    float vs = 0.f;
    for (int i = tid; i < HH; i += 256) { float d = x[i] - mean; vs += d * d; }
    red[tid] = vs; __syncthreads();
    for (int st = 128; st > 0; st >>= 1) { if (tid < st) red[tid] += red[tid + st]; __syncthreads(); }
    float rstd = rsqrtf(red[0] / HH + 1e-5f);
    __syncthreads();
    for (int i = tid; i < HH; i += 256)
        out[(size_t)row * HH + i] = (x[i] - mean) * rstd * g[i] + b[i];
}

// ---------------------------------------------------------------------------
// Tiled flash-style band+global-key attention.
// Block = 256 threads handles 64 queries for one (b, h).
// Key tiles: tile 0 = global keys [0,16); band tiles of 64 covering
// [max(16, c0-128), min(2047, c0+63+128)]. Online softmax across tiles.
// LDS: Qt[d][q] (64x64), KtPs (64x68, Kt[d][k] then reused as Ps[k][q]),
// Vs[k][d] (64x68). 53248 B -> 3 blocks/CU.
__global__ __launch_bounds__(256) void band_attn_tiled(const float* __restrict__ q,
    const float* __restrict__ k, const float* __restrict__ v, float* __restrict__ o)
{
    __shared__ float Qt[64][64];    // [d][q]
    __shared__ float KtPs[64][68];  // phase A: Kt[d][k]; phase B: Ps[k][q]
    __shared__ float Vs[64][68];    // [k][d]
    __shared__ float m_sh[64], l_sh[64], alpha_sh[64], mn_sh[64];
    __shared__ float pred[4][64];   // reused: partial max, then partial sum

    int h  = blockIdx.x;
    int c0 = blockIdx.y * 64;
    int b  = blockIdx.z;
    int tid = threadIdx.x;
    int tx = tid & 15, ty = tid >> 4;

    // Load Q chunk transposed: Qt[d][q]
    {
        int r  = tid >> 2;          // query 0..63
        int dq = (tid & 3) * 16;    // d quarter
        const float* qp = q + (((size_t)b * SS + c0 + r) * NHH + h) * DD + dq;
        #pragma unroll
        for (int t = 0; t < 16; t++) Qt[dq + t][r] = qp[t];
    }
    if (tid < 64) { m_sh[tid] = -1e30f; l_sh[tid] = 0.f; }

    float O[4][4] = {};

    int lo = c0 - WW; if (lo < GG) lo = GG;
    int hi = c0 + 63 + WW; if (hi > SS - 1) hi = SS - 1;
    int nband = (hi - lo + 1 + 63) / 64;

    for (int t = 0; t <= nband; t++) {
        int kbase = (t == 0) ? 0 : lo + (t - 1) * 64;
        int kend  = (t == 0) ? GG : ((kbase + 64 < hi + 1) ? kbase + 64 : hi + 1);

        __syncthreads();  // previous tile's Ps/Vs reads done
        // Load K tile transposed + V tile
        {
            int r  = tid >> 2;
            int dq = (tid & 3) * 16;
            int kpos = kbase + r;
            if (kpos < kend) {
                const float* kp = k + (((size_t)b * SS + kpos) * NHH + h) * DD + dq;
                const float* vp = v + (((size_t)b * SS + kpos) * NHH + h) * DD + dq;
                #pragma unroll
                for (int u = 0; u < 16; u++) KtPs[dq + u][r] = kp[u];
                #pragma unroll
                for (int u = 0; u < 4; u++)
                    *(float4*)&Vs[r][dq + 4 * u] = *(const float4*)&vp[4 * u];
            } else {
                // zero V so garbage (possible NaN bits) can't leak via 0*NaN
                #pragma unroll
                for (int u = 0; u < 4; u++)
                    *(float4*)&Vs[r][dq + 4 * u] = make_float4(0.f, 0.f, 0.f, 0.f);
            }
        }
        __syncthreads();

        // S[4q][4k] = Qt^T @ Kt
        float Sv[4][4] = {};
        for (int d = 0; d < 64; d++) {
            float4 av = *(const float4*)&Qt[d][ty * 4];
            float4 bv = *(const float4*)&KtPs[d][tx * 4];
            float a_[4] = {av.x, av.y, av.z, av.w};
            float b_[4] = {bv.x, bv.y, bv.z, bv.w};
            #pragma unroll
            for (int i = 0; i < 4; i++)
                #pragma unroll
                for (int j = 0; j < 4; j++) Sv[i][j] += a_[i] * b_[j];
        }
        // Mask
        #pragma unroll
        for (int i = 0; i < 4; i++) {
            int qg = c0 + ty * 4 + i;
            #pragma unroll
            for (int j = 0; j < 4; j++) {
                int kg = kbase + tx * 4 + j;
                bool ok = (kg < kend) &&
                          (t == 0 || (kg - qg <= WW && qg - kg <= WW));
                if (!ok) Sv[i][j] = -1e9f;
            }
        }
        __syncthreads();  // Kt reads done; safe to overwrite as Ps

        // Write S transposed: Ps[k][q]
        #pragma unroll
        for (int j = 0; j < 4; j++) {
            float4 w = make_float4(Sv[0][j], Sv[1][j], Sv[2][j], Sv[3][j]);
            *(float4*)&KtPs[tx * 4 + j][ty * 4] = w;
        }
        __syncthreads();

        // Row max (4 partials x 64 queries)
        {
            int qq = tid & 63, part = tid >> 6;
            float mx = -1e30f;
            for (int kk = part * 16; kk < part * 16 + 16; kk++)
                mx = fmaxf(mx, KtPs[kk][qq]);
            pred[part][qq] = mx;
        }
        __syncthreads();
        if (tid < 64) {
            float mt = fmaxf(fmaxf(pred[0][tid], pred[1][tid]),
                             fmaxf(pred[2][tid], pred[3][tid]));
            float mo = m_sh[tid];
            float mnew = fmaxf(mo, mt);
            alpha_sh[tid] = __expf(mo - mnew);
            mn_sh[tid] = mnew;
            m_sh[tid] = mnew;
        }
        __syncthreads();
        // exp + row sum
        {
            int qq = tid & 63, part = tid >> 6;
            float mnew = mn_sh[qq];
            float s = 0.f;
            for (int kk = part * 16; kk < part * 16 + 16; kk++) {
                float p = __expf(KtPs[kk][qq] - mnew);
                KtPs[kk][qq] = p;
                s += p;
            }
            pred[part][qq] = s;
        }
        __syncthreads();
        if (tid < 64)
            l_sh[tid] = l_sh[tid] * alpha_sh[tid] +
                        pred[0][tid] + pred[1][tid] + pred[2][tid] + pred[3][tid];

        // O = O*alpha + P @ V
        float al[4];
        #pragma unroll
        for (int i = 0; i < 4; i++) al[i] = alpha_sh[ty * 4 + i];
        #pragma unroll
        for (int i = 0; i < 4; i++)
            #pragma unroll
            for (int j = 0; j < 4; j++) O[i][j] *= al[i];
        for (int kk = 0; kk < 64; kk++) {
            float4 av = *(const float4*)&KtPs[kk][ty * 4];
            float4 bv = *(const float4*)&Vs[kk][tx * 4];
            float a_[4] = {av.x, av.y, av.z, av.w};
            float b_[4] = {bv.x, bv.y, bv.z, bv.w};
            #pragma unroll
            for (int i = 0; i < 4; i++)
                #pragma unroll
                for (int j = 0; j < 4; j++) O[i][j] += a_[i] * b_[j];
        }
    }
    __syncthreads();

    #pragma unroll
    for (int i = 0; i < 4; i++) {
        int qg = c0 + ty * 4 + i;
        float invl = 1.f / l_sh[ty * 4 + i];
        float4 w = make_float4(O[i][0] * invl, O[i][1] * invl,
                               O[i][2] * invl, O[i][3] * invl);
        *(float4*)&o[(((size_t)b * SS + qg) * NHH + h) * DD + tx * 4] = w;
    }
}

// ---------------------------------------------------------------------------
// Global-query rows (s < G): full softmax attention over all S keys.
__global__ __launch_bounds__(256) void global_attn_kernel(const float* __restrict__ q,
    const float* __restrict__ k, const float* __restrict__ v, float* __restrict__ o)
{
    int g = blockIdx.x, h = blockIdx.y, b = blockIdx.z;
    __shared__ float sc[SS];
    __shared__ float qs[DD];
    __shared__ float red[256];
    int tid = threadIdx.x;
    if (tid < DD) qs[tid] = q[(((size_t)b * SS + g) * NHH + h) * DD + tid];
    __syncthreads();
    for (int s0 = tid; s0 < SS; s0 += 256) {
        const float* kp = k + (((size_t)b * SS + s0) * NHH + h) * DD;
        float d0 = 0.f;
        #pragma unroll
        for (int d = 0; d < DD; d++) d0 += qs[d] * kp[d];
        sc[s0] = d0;
    }
    __syncthreads();
    float mx = -INFINITY;
    for (int s0 = tid; s0 < SS; s0 += 256) mx = fmaxf(mx, sc[s0]);
    red[tid] = mx; __syncthreads();
    for (int st = 128; st > 0; st >>= 1) { if (tid < st) red[tid] = fmaxf(red[tid], red[tid + st]); __syncthreads(); }
    mx = red[0]; __syncthreads();
    float sum = 0.f;
    for (int s0 = tid; s0 < SS; s0 += 256) { float p = __expf(sc[s0] - mx); sc[s0] = p; sum += p; }
    red[tid] = sum; __syncthreads();
    for (int st = 128; st > 0; st >>= 1) { if (tid < st) red[tid] += red[tid + st]; __syncthreads(); }
    float inv = 1.f / red[0];
    __syncthreads();
    int d = tid & 63, grp = tid >> 6;
    float acc = 0.f;
    for (int s0 = grp; s0 < SS; s0 += 4)
        acc += sc[s0] * v[(((size_t)b * SS + s0) * NHH + h) * DD + d];
    red[tid] = acc; __syncthreads();
    if (grp == 0) {
        float r = red[d] + red[64 + d] + red[128 + d] + red[192 + d];
        o[(((size_t)b * SS + g) * NHH + h) * DD + d] = r * inv;
    }
}

// ---------------------------------------------------------------------------
// Pair head: out[row,:] = concat(x[b,i,:], x[b,j,:]) @ Wh + bh
__global__ __launch_bounds__(256) void pair_head_kernel(const float* __restrict__ x,
    const int* __restrict__ pairs, const float* __restrict__ Wh,
    const float* __restrict__ bh, float* __restrict__ out)
{
    int row = blockIdx.x;
    int b = row / PP;
    int i = pairs[row * 2 + 0];
    int j = pairs[row * 2 + 1];
    const float* xi = x + ((size_t)b * SS + i) * HH;
    const float* xj = x + ((size_t)b * SS + j) * HH;
    float acc[NLL] = {};
    for (int e = threadIdx.x; e < 2 * HH; e += 256) {
        float val = (e < HH) ? xi[e] : xj[e - HH];
        #pragma unroll
        for (int c = 0; c < NLL; c++) acc[c] += val * Wh[e * NLL + c];
    }
    __shared__ float red[NLL * 256];
    #pragma unroll
    for (int c = 0; c < NLL; c++) red[c * 256 + threadIdx.x] = acc[c];
    __syncthreads();
    for (int st = 128; st > 0; st >>= 1) {
        if (threadIdx.x < st)
            #pragma unroll
            for (int c = 0; c < NLL; c++)
                red[c * 256 + threadIdx.x] += red[c * 256 + threadIdx.x + st];
        __syncthreads();
    }
    if (threadIdx.x < NLL) out[row * NLL + threadIdx.x] = red[threadIdx.x * 256] + bh[threadIdx.x];
}

// ---------------------------------------------------------------------------
extern "C" void kernel_launch(void* const* d_in, const int* in_sizes, int n_in,
                              void* d_out, int out_size, void* d_ws, size_t ws_size,
                              hipStream_t stream)
{
    const int*   input_ids    = (const int*)d_in[0];
    const int*   pair_indices = (const int*)d_in[1];
    const float* emb   = (const float*)d_in[2];
    const float* Wq    = (const float*)d_in[3];
    const float* bq    = (const float*)d_in[4];
    const float* Wk    = (const float*)d_in[5];
    const float* bk    = (const float*)d_in[6];
    const float* Wv    = (const float*)d_in[7];
    const float* bv    = (const float*)d_in[8];
    const float* Wo    = (const float*)d_in[9];
    const float* bo    = (const float*)d_in[10];
    const float* ln1_g = (const float*)d_in[11];
    const float* ln1_b = (const float*)d_in[12];
    const float* Wf1   = (const float*)d_in[13];
    const float* bf1   = (const float*)d_in[14];
    const float* Wf2   = (const float*)d_in[15];
    const float* bf2   = (const float*)d_in[16];
    const float* ln2_g = (const float*)d_in[17];
    const float* ln2_b = (const float*)d_in[18];
    const float* Wh    = (const float*)d_in[19];
    const float* bh    = (const float*)d_in[20];

    const size_t R = (size_t)BB * SS;   // 4096 rows
    float* ws = (float*)d_ws;
    float* x  = ws;              // R*H
    float* q  = x + R * HH;      // R*H
    float* k  = q + R * HH;      // R*H
    float* v  = k + R * HH;      // R*H
    float* o  = v + R * HH;      // R*H
    float* t1 = o + R * HH;      // R*H
    float* hb = q;               // R*FF aliases q..o (exactly 4*R*H floats)

    embed_kernel<<<dim3((int)R), 256, 0, stream>>>(input_ids, emb, x);

    dim3 gHH(HH / 64, (int)R / 64);
    dim3 gFF(FF / 64, (int)R / 64);
    for (int l = 0; l < LL; l++) {
        const float* lWq = Wq + (size_t)l * HH * HH;  const float* lbq = bq + (size_t)l * HH;
        const float* lWk = Wk + (size_t)l * HH * HH;  const float* lbk = bk + (size_t)l * HH;
        const float* lWv = Wv + (size_t)l * HH * HH;  const float* lbv = bv + (size_t)l * HH;
        const float* lWo = Wo + (size_t)l * HH * HH;  const float* lbo = bo + (size_t)l * HH;
        const float* lg1 = ln1_g + (size_t)l * HH;    const float* lb1 = ln1_b + (size_t)l * HH;
        const float* lWf1 = Wf1 + (size_t)l * HH * FF; const float* lbf1 = bf1 + (size_t)l * FF;
        const float* lWf2 = Wf2 + (size_t)l * FF * HH; const float* lbf2 = bf2 + (size_t)l * HH;
        const float* lg2 = ln2_g + (size_t)l * HH;    const float* lb2 = ln2_b + (size_t)l * HH;

        gemm_kernel<<<gHH, 256, 0, stream>>>(x, lWq, lbq, nullptr, q, (int)R, HH, HH, 1, 0.125f);
        gemm_kernel<<<gHH, 256, 0, stream>>>(x, lWk, lbk, nullptr, k, (int)R, HH, HH, 0, 0.f);
        gemm_kernel<<<gHH, 256, 0, stream>>>(x, lWv, lbv, nullptr, v, (int)R, HH, HH, 0, 0.f);

        band_attn_tiled<<<dim3(NHH, SS / 64, BB), 256, 0, stream>>>(q, k, v, o);
        global_attn_kernel<<<dim3(GG, NHH, BB), 256, 0, stream>>>(q, k, v, o);

        gemm_kernel<<<gHH, 256, 0, stream>>>(o, lWo, lbo, x, t1, (int)R, HH, HH, 2, 0.f);
        ln_kernel<<<dim3((int)R), 256, 0, stream>>>(t1, lg1, lb1, x);

        gemm_kernel<<<gFF, 256, 0, stream>>>(x, lWf1, lbf1, nullptr, hb, (int)R, FF, HH, 3, 0.f);
        gemm_kernel<<<gHH, 256, 0, stream>>>(hb, lWf2, lbf2, x, t1, (int)R, HH, FF, 2, 0.f);
        ln_kernel<<<dim3((int)R), 256, 0, stream>>>(t1, lg2, lb2, x);
    }

    pair_head_kernel<<<dim3(BB * PP), 256, 0, stream>>>(x, pair_indices, Wh, bh, (float*)d_out);
}

// Round 3
// 2120.734 us; speedup vs baseline: 4.7147x; 2.8286x over previous
//
#include <hip/hip_runtime.h>
#include <math.h>

#define BB 2
#define SS 2048
#define HH 768
#define NHH 12
#define LL 4
#define DD 64
#define WW 128
#define GG 16
#define PP 128
#define NLL 3
#define FF 3072

typedef __bf16 bf16x8 __attribute__((ext_vector_type(8)));
typedef __bf16 bf16x4 __attribute__((ext_vector_type(4)));
typedef float f32x4 __attribute__((ext_vector_type(4)));

// ---------------------------------------------------------------------------
// Embedding gather: x[row,:] = emb[ids[row],:], plus bf16 copy.
__global__ __launch_bounds__(256) void embed_kernel(const int* __restrict__ ids,
    const float* __restrict__ emb, float* __restrict__ x, __bf16* __restrict__ xb)
{
    int row = blockIdx.x;
    int id = ids[row];
    const float* e = emb + (size_t)id * HH;
    float* xp = x + (size_t)row * HH;
    __bf16* xbp = xb + (size_t)row * HH;
    for (int i = threadIdx.x; i < HH; i += 256) {
        float v = e[i];
        xp[i] = v;
        xbp[i] = (__bf16)v;
    }
}

// ---------------------------------------------------------------------------
// Pack per-layer q,k,v biases into [L][3*H]
__global__ __launch_bounds__(256) void pack_bias_kernel(const float* __restrict__ bq,
    const float* __restrict__ bk, const float* __restrict__ bv, float* __restrict__ dst)
{
    int l = blockIdx.x;
    for (int i = threadIdx.x; i < HH; i += 256) {
        dst[(size_t)l * 3 * HH + i]          = bq[(size_t)l * HH + i];
        dst[(size_t)l * 3 * HH + HH + i]     = bk[(size_t)l * HH + i];
        dst[(size_t)l * 3 * HH + 2 * HH + i] = bv[(size_t)l * HH + i];
    }
}

// ---------------------------------------------------------------------------
// Transpose + fp32->bf16: src [K][N] fp32 -> dst [N][K] bf16. blockIdx.z = layer.
__global__ __launch_bounds__(256) void transpose_bf16_kernel(const float* __restrict__ src,
    __bf16* __restrict__ dst, int K, int N, size_t src_ls, size_t dst_ls)
{
    int l = blockIdx.z;
    src += (size_t)l * src_ls;
    dst += (size_t)l * dst_ls;
    __shared__ float t[32][33];
    int tx = threadIdx.x & 31, ty = threadIdx.x >> 5;  // 32 x 8
    int n0 = blockIdx.x * 32, k0 = blockIdx.y * 32;
    for (int i = ty; i < 32; i += 8)
        t[i][tx] = src[(size_t)(k0 + i) * N + n0 + tx];
    __syncthreads();
    for (int i = ty; i < 32; i += 8)
        dst[(size_t)(n0 + i) * K + k0 + tx] = (__bf16)t[tx][i];
}

// ---------------------------------------------------------------------------
// bf16 MFMA GEMM: C[M,N] = epi(A[M,K] @ Bt[N,K]^T + bias)
// 128x128 tile, BK=32, 4 waves (2x2 of 64x64), 16x16x32 MFMA.
// epi: 2 = +res, fp32 out | 3 = gelu, bf16 out | 4 = qkv-split fp32 out
//      (z = col/768; z==0 scaled; out[z*M + row][col%768])
__global__ __launch_bounds__(256) void mfma_gemm(
    const __bf16* __restrict__ A, const __bf16* __restrict__ Bt,
    const float* __restrict__ bias, const float* __restrict__ res,
    void* __restrict__ outv, int M, int N, int K, int epi, float scale)
{
    __shared__ __bf16 As[128 * 32];
    __shared__ __bf16 Bs[128 * 32];
    int tid = threadIdx.x;
    int tileM = blockIdx.y * 128, tileN = blockIdx.x * 128;
    int wave = tid >> 6, lane = tid & 63;
    int wm = (wave >> 1) * 64, wn = (wave & 1) * 64;
    int lr = lane & 15, quad = lane >> 4;

    int s0 = tid, s1 = tid + 256;
    int r0 = s0 >> 2, ko0 = (s0 & 3) * 8;
    int r1 = s1 >> 2, ko1 = (s1 & 3) * 8;
    const __bf16* Ap0 = A + (size_t)(tileM + r0) * K + ko0;
    const __bf16* Ap1 = A + (size_t)(tileM + r1) * K + ko1;
    const __bf16* Bp0 = Bt + (size_t)(tileN + r0) * K + ko0;
    const __bf16* Bp1 = Bt + (size_t)(tileN + r1) * K + ko1;

    f32x4 acc[4][4] = {};

    bf16x8 ra0 = *(const bf16x8*)&Ap0[0];
    bf16x8 ra1 = *(const bf16x8*)&Ap1[0];
    bf16x8 rb0 = *(const bf16x8*)&Bp0[0];
    bf16x8 rb1 = *(const bf16x8*)&Bp1[0];

    for (int k0 = 0; k0 < K; k0 += 32) {
        __syncthreads();
        *(bf16x8*)&As[s0 * 8] = ra0;
        *(bf16x8*)&As[s1 * 8] = ra1;
        *(bf16x8*)&Bs[s0 * 8] = rb0;
        *(bf16x8*)&Bs[s1 * 8] = rb1;
        __syncthreads();
        int kn = k0 + 32;
        if (kn < K) {  // prefetch next tile while MFMAs run
            ra0 = *(const bf16x8*)&Ap0[kn];
            ra1 = *(const bf16x8*)&Ap1[kn];
            rb0 = *(const bf16x8*)&Bp0[kn];
            rb1 = *(const bf16x8*)&Bp1[kn];
        }
        bf16x8 af[4], bfr[4];
        #pragma unroll
        for (int i = 0; i < 4; i++) {
            af[i]  = *(const bf16x8*)&As[(wm + i * 16 + lr) * 32 + quad * 8];
            bfr[i] = *(const bf16x8*)&Bs[(wn + i * 16 + lr) * 32 + quad * 8];
        }
        #pragma unroll
        for (int mi = 0; mi < 4; mi++)
            #pragma unroll
            for (int ni = 0; ni < 4; ni++)
                acc[mi][ni] = __builtin_amdgcn_mfma_f32_16x16x32_bf16(
                    af[mi], bfr[ni], acc[mi][ni], 0, 0, 0);
    }

    // Epilogue. C/D layout: col = lane&15, row = quad*4 + reg.
    int zq = (epi == 4) ? tileN / HH : 0;
    #pragma unroll
    for (int mi = 0; mi < 4; mi++) {
        #pragma unroll
        for (int reg = 0; reg < 4; reg++) {
            int row = tileM + wm + mi * 16 + quad * 4 + reg;
            #pragma unroll
            for (int ni = 0; ni < 4; ni++) {
                int col = tileN + wn + ni * 16 + lr;
                float v = acc[mi][ni][reg] + bias[col];
                if (epi == 2) {
                    v += res[(size_t)row * N + col];
                    ((float*)outv)[(size_t)row * N + col] = v;
                } else if (epi == 3) {
                    float t = 0.7978845608028654f * (v + 0.044715f * v * v * v);
                    v = 0.5f * v * (1.0f + tanhf(t));
                    ((__bf16*)outv)[(size_t)row * N + col] = (__bf16)v;
                } else {  // epi == 4
                    if (zq == 0) v *= scale;
                    ((float*)outv)[((size_t)zq * M + row) * HH + (col - zq * HH)] = v;
                }
            }
        }
    }
}

// ---------------------------------------------------------------------------
// LayerNorm over H per row; writes fp32 + bf16. Safe for in==out.
__global__ __launch_bounds__(256) void ln_kernel(const float* __restrict__ in,
    const float* __restrict__ g, const float* __restrict__ b,
    float* __restrict__ out, __bf16* __restrict__ outb)
{
    int row = blockIdx.x;
    __shared__ float red[256];
    const float* x = in + (size_t)row * HH;
    int tid = threadIdx.x;
    float s = 0.f;
    for (int i = tid; i < HH; i += 256) s += x[i];
    red[tid] = s; __syncthreads();
    for (int st = 128; st > 0; st >>= 1) { if (tid < st) red[tid] += red[tid + st]; __syncthreads(); }
    float mean = red[0] / HH;
    __syncthreads();
    float vs = 0.f;
    for (int i = tid; i < HH; i += 256) { float d = x[i] - mean; vs += d * d; }
    red[tid] = vs; __syncthreads();
    for (int st = 128; st > 0; st >>= 1) { if (tid < st) red[tid] += red[tid + st]; __syncthreads(); }
    float rstd = rsqrtf(red[0] / HH + 1e-5f);
    __syncthreads();
    for (int i = tid; i < HH; i += 256) {
        float v = (x[i] - mean) * rstd * g[i] + b[i];
        out[(size_t)row * HH + i] = v;
        outb[(size_t)row * HH + i] = (__bf16)v;
    }
}

// ---------------------------------------------------------------------------
// Tiled flash-style band+global-key attention (fp32 math, bf16 output).
__global__ __launch_bounds__(256) void band_attn_tiled(const float* __restrict__ q,
    const float* __restrict__ k, const float* __restrict__ v, __bf16* __restrict__ ob)
{
    __shared__ float Qt[64][64];
    __shared__ float KtPs[64][68];
    __shared__ float Vs[64][68];
    __shared__ float m_sh[64], l_sh[64], alpha_sh[64], mn_sh[64];
    __shared__ float pred[4][64];

    int h  = blockIdx.x;
    int c0 = blockIdx.y * 64;
    int b  = blockIdx.z;
    int tid = threadIdx.x;
    int tx = tid & 15, ty = tid >> 4;

    {
        int r  = tid >> 2;
        int dq = (tid & 3) * 16;
        const float* qp = q + (((size_t)b * SS + c0 + r) * NHH + h) * DD + dq;
        #pragma unroll
        for (int t = 0; t < 16; t++) Qt[dq + t][r] = qp[t];
    }
    if (tid < 64) { m_sh[tid] = -1e30f; l_sh[tid] = 0.f; }

    float O[4][4] = {};

    int lo = c0 - WW; if (lo < GG) lo = GG;
    int hi = c0 + 63 + WW; if (hi > SS - 1) hi = SS - 1;
    int nband = (hi - lo + 1 + 63) / 64;

    for (int t = 0; t <= nband; t++) {
        int kbase = (t == 0) ? 0 : lo + (t - 1) * 64;
        int kend  = (t == 0) ? GG : ((kbase + 64 < hi + 1) ? kbase + 64 : hi + 1);

        __syncthreads();
        {
            int r  = tid >> 2;
            int dq = (tid & 3) * 16;
            int kpos = kbase + r;
            if (kpos < kend) {
                const float* kp = k + (((size_t)b * SS + kpos) * NHH + h) * DD + dq;
                const float* vp = v + (((size_t)b * SS + kpos) * NHH + h) * DD + dq;
                #pragma unroll
                for (int u = 0; u < 16; u++) KtPs[dq + u][r] = kp[u];
                #pragma unroll
                for (int u = 0; u < 4; u++)
                    *(float4*)&Vs[r][dq + 4 * u] = *(const float4*)&vp[4 * u];
            } else {
                #pragma unroll
                for (int u = 0; u < 4; u++)
                    *(float4*)&Vs[r][dq + 4 * u] = make_float4(0.f, 0.f, 0.f, 0.f);
            }
        }
        __syncthreads();

        float Sv[4][4] = {};
        for (int d = 0; d < 64; d++) {
            float4 av = *(const float4*)&Qt[d][ty * 4];
            float4 bv = *(const float4*)&KtPs[d][tx * 4];
            float a_[4] = {av.x, av.y, av.z, av.w};
            float b_[4] = {bv.x, bv.y, bv.z, bv.w};
            #pragma unroll
            for (int i = 0; i < 4; i++)
                #pragma unroll
                for (int j = 0; j < 4; j++) Sv[i][j] += a_[i] * b_[j];
        }
        #pragma unroll
        for (int i = 0; i < 4; i++) {
            int qg = c0 + ty * 4 + i;
            #pragma unroll
            for (int j = 0; j < 4; j++) {
                int kg = kbase + tx * 4 + j;
                bool ok = (kg < kend) &&
                          (t == 0 || (kg - qg <= WW && qg - kg <= WW));
                if (!ok) Sv[i][j] = -1e9f;
            }
        }
        __syncthreads();

        #pragma unroll
        for (int j = 0; j < 4; j++) {
            float4 w = make_float4(Sv[0][j], Sv[1][j], Sv[2][j], Sv[3][j]);
            *(float4*)&KtPs[tx * 4 + j][ty * 4] = w;
        }
        __syncthreads();

        {
            int qq = tid & 63, part = tid >> 6;
            float mx = -1e30f;
            for (int kk = part * 16; kk < part * 16 + 16; kk++)
                mx = fmaxf(mx, KtPs[kk][qq]);
            pred[part][qq] = mx;
        }
        __syncthreads();
        if (tid < 64) {
            float mt = fmaxf(fmaxf(pred[0][tid], pred[1][tid]),
                             fmaxf(pred[2][tid], pred[3][tid]));
            float mo = m_sh[tid];
            float mnew = fmaxf(mo, mt);
            alpha_sh[tid] = __expf(mo - mnew);
            mn_sh[tid] = mnew;
            m_sh[tid] = mnew;
        }
        __syncthreads();
        {
            int qq = tid & 63, part = tid >> 6;
            float mnew = mn_sh[qq];
            float s = 0.f;
            for (int kk = part * 16; kk < part * 16 + 16; kk++) {
                float p = __expf(KtPs[kk][qq] - mnew);
                KtPs[kk][qq] = p;
                s += p;
            }
            pred[part][qq] = s;
        }
        __syncthreads();
        if (tid < 64)
            l_sh[tid] = l_sh[tid] * alpha_sh[tid] +
                        pred[0][tid] + pred[1][tid] + pred[2][tid] + pred[3][tid];

        float al[4];
        #pragma unroll
        for (int i = 0; i < 4; i++) al[i] = alpha_sh[ty * 4 + i];
        #pragma unroll
        for (int i = 0; i < 4; i++)
            #pragma unroll
            for (int j = 0; j < 4; j++) O[i][j] *= al[i];
        for (int kk = 0; kk < 64; kk++) {
            float4 av = *(const float4*)&KtPs[kk][ty * 4];
            float4 bv = *(const float4*)&Vs[kk][tx * 4];
            float a_[4] = {av.x, av.y, av.z, av.w};
            float b_[4] = {bv.x, bv.y, bv.z, bv.w};
            #pragma unroll
            for (int i = 0; i < 4; i++)
                #pragma unroll
                for (int j = 0; j < 4; j++) O[i][j] += a_[i] * b_[j];
        }
    }
    __syncthreads();

    #pragma unroll
    for (int i = 0; i < 4; i++) {
        int qg = c0 + ty * 4 + i;
        float invl = 1.f / l_sh[ty * 4 + i];
        bf16x4 w4;
        w4[0] = (__bf16)(O[i][0] * invl);
        w4[1] = (__bf16)(O[i][1] * invl);
        w4[2] = (__bf16)(O[i][2] * invl);
        w4[3] = (__bf16)(O[i][3] * invl);
        *(bf16x4*)&ob[(((size_t)b * SS + qg) * NHH + h) * DD + tx * 4] = w4;
    }
}

// ---------------------------------------------------------------------------
// Global-query rows (s < G): full softmax over all S keys; bf16 out.
__global__ __launch_bounds__(256) void global_attn_kernel(const float* __restrict__ q,
    const float* __restrict__ k, const float* __restrict__ v, __bf16* __restrict__ ob)
{
    int g = blockIdx.x, h = blockIdx.y, b = blockIdx.z;
    __shared__ float sc[SS];
    __shared__ float qs[DD];
    __shared__ float red[256];
    int tid = threadIdx.x;
    if (tid < DD) qs[tid] = q[(((size_t)b * SS + g) * NHH + h) * DD + tid];
    __syncthreads();
    for (int s0 = tid; s0 < SS; s0 += 256) {
        const float* kp = k + (((size_t)b * SS + s0) * NHH + h) * DD;
        float d0 = 0.f;
        #pragma unroll
        for (int d = 0; d < DD; d++) d0 += qs[d] * kp[d];
        sc[s0] = d0;
    }
    __syncthreads();
    float mx = -INFINITY;
    for (int s0 = tid; s0 < SS; s0 += 256) mx = fmaxf(mx, sc[s0]);
    red[tid] = mx; __syncthreads();
    for (int st = 128; st > 0; st >>= 1) { if (tid < st) red[tid] = fmaxf(red[tid], red[tid + st]); __syncthreads(); }
    mx = red[0]; __syncthreads();
    float sum = 0.f;
    for (int s0 = tid; s0 < SS; s0 += 256) { float p = __expf(sc[s0] - mx); sc[s0] = p; sum += p; }
    red[tid] = sum; __syncthreads();
    for (int st = 128; st > 0; st >>= 1) { if (tid < st) red[tid] += red[tid + st]; __syncthreads(); }
    float inv = 1.f / red[0];
    __syncthreads();
    int d = tid & 63, grp = tid >> 6;
    float acc = 0.f;
    for (int s0 = grp; s0 < SS; s0 += 4)
        acc += sc[s0] * v[(((size_t)b * SS + s0) * NHH + h) * DD + d];
    red[tid] = acc; __syncthreads();
    if (grp == 0) {
        float r = red[d] + red[64 + d] + red[128 + d] + red[192 + d];
        ob[(((size_t)b * SS + g) * NHH + h) * DD + d] = (__bf16)(r * inv);
    }
}

// ---------------------------------------------------------------------------
// Pair head: out[row,:] = concat(x[b,i,:], x[b,j,:]) @ Wh + bh
__global__ __launch_bounds__(256) void pair_head_kernel(const float* __restrict__ x,
    const int* __restrict__ pairs, const float* __restrict__ Wh,
    const float* __restrict__ bh, float* __restrict__ out)
{
    int row = blockIdx.x;
    int b = row / PP;
    int i = pairs[row * 2 + 0];
    int j = pairs[row * 2 + 1];
    const float* xi = x + ((size_t)b * SS + i) * HH;
    const float* xj = x + ((size_t)b * SS + j) * HH;
    float acc[NLL] = {};
    for (int e = threadIdx.x; e < 2 * HH; e += 256) {
        float val = (e < HH) ? xi[e] : xj[e - HH];
        #pragma unroll
        for (int c = 0; c < NLL; c++) acc[c] += val * Wh[e * NLL + c];
    }
    __shared__ float red[NLL * 256];
    #pragma unroll
    for (int c = 0; c < NLL; c++) red[c * 256 + threadIdx.x] = acc[c];
    __syncthreads();
    for (int st = 128; st > 0; st >>= 1) {
        if (threadIdx.x < st)
            #pragma unroll
            for (int c = 0; c < NLL; c++)
                red[c * 256 + threadIdx.x] += red[c * 256 + threadIdx.x + st];
        __syncthreads();
    }
    if (threadIdx.x < NLL) out[row * NLL + threadIdx.x] = red[threadIdx.x * 256] + bh[threadIdx.x];
}

// ---------------------------------------------------------------------------
extern "C" void kernel_launch(void* const* d_in, const int* in_sizes, int n_in,
                              void* d_out, int out_size, void* d_ws, size_t ws_size,
                              hipStream_t stream)
{
    const int*   input_ids    = (const int*)d_in[0];
    const int*   pair_indices = (const int*)d_in[1];
    const float* emb   = (const float*)d_in[2];
    const float* Wq    = (const float*)d_in[3];
    const float* bq    = (const float*)d_in[4];
    const float* Wk    = (const float*)d_in[5];
    const float* bk    = (const float*)d_in[6];
    const float* Wv    = (const float*)d_in[7];
    const float* bv    = (const float*)d_in[8];
    const float* Wo    = (const float*)d_in[9];
    const float* bo    = (const float*)d_in[10];
    const float* ln1_g = (const float*)d_in[11];
    const float* ln1_b = (const float*)d_in[12];
    const float* Wf1   = (const float*)d_in[13];
    const float* bf1   = (const float*)d_in[14];
    const float* Wf2   = (const float*)d_in[15];
    const float* bf2   = (const float*)d_in[16];
    const float* ln2_g = (const float*)d_in[17];
    const float* ln2_b = (const float*)d_in[18];
    const float* Wh    = (const float*)d_in[19];
    const float* bh    = (const float*)d_in[20];

    const size_t R = (size_t)BB * SS;                  // 4096
    const size_t LWS = 4 * (size_t)HH * HH + 2 * (size_t)HH * FF;  // 7077888 el/layer

    char* w = (char*)d_ws;
    float* x      = (float*)w;  w += R * HH * 4;
    float* t1     = (float*)w;  w += R * HH * 4;
    float* qkv    = (float*)w;  w += 3 * R * HH * 4;
    __bf16* x_bf  = (__bf16*)w; w += R * HH * 2;
    __bf16* o_bf  = (__bf16*)w; w += R * HH * 2;
    float* bias_qkv = (float*)w; w += LL * 3 * HH * 4;
    __bf16* Wbf   = (__bf16*)w; w += LL * LWS * 2;
    __bf16* hb_bf = (__bf16*)qkv;   // aliases dead q/k/v during FFN
    float* qf = qkv;
    float* kf = qkv + R * HH;
    float* vf = qkv + 2 * R * HH;

    // --- once per launch: weight conversion (transpose + bf16) ---
    pack_bias_kernel<<<dim3(LL), 256, 0, stream>>>(bq, bk, bv, bias_qkv);
    size_t hh = (size_t)HH * HH, hf = (size_t)HH * FF;
    transpose_bf16_kernel<<<dim3(HH/32, HH/32, LL), 256, 0, stream>>>(Wq, Wbf,            HH, HH, hh, LWS);
    transpose_bf16_kernel<<<dim3(HH/32, HH/32, LL), 256, 0, stream>>>(Wk, Wbf + hh,       HH, HH, hh, LWS);
    transpose_bf16_kernel<<<dim3(HH/32, HH/32, LL), 256, 0, stream>>>(Wv, Wbf + 2 * hh,   HH, HH, hh, LWS);
    transpose_bf16_kernel<<<dim3(HH/32, HH/32, LL), 256, 0, stream>>>(Wo, Wbf + 3 * hh,   HH, HH, hh, LWS);
    transpose_bf16_kernel<<<dim3(FF/32, HH/32, LL), 256, 0, stream>>>(Wf1, Wbf + 4 * hh,  HH, FF, hf, LWS);
    transpose_bf16_kernel<<<dim3(HH/32, FF/32, LL), 256, 0, stream>>>(Wf2, Wbf + 4 * hh + hf, FF, HH, hf, LWS);

    embed_kernel<<<dim3((int)R), 256, 0, stream>>>(input_ids, emb, x, x_bf);

    for (int l = 0; l < LL; l++) {
        __bf16* Wl = Wbf + (size_t)l * LWS;
        const float* lbo  = bo  + (size_t)l * HH;
        const float* lg1  = ln1_g + (size_t)l * HH;  const float* lb1 = ln1_b + (size_t)l * HH;
        const float* lbf1 = bf1 + (size_t)l * FF;
        const float* lbf2 = bf2 + (size_t)l * HH;
        const float* lg2  = ln2_g + (size_t)l * HH;  const float* lb2 = ln2_b + (size_t)l * HH;

        // fused QKV: A[R,768] x Wqkv^T[2304,768] -> q,k,v fp32 (q scaled)
        mfma_gemm<<<dim3(3 * HH / 128, R / 128), 256, 0, stream>>>(
            x_bf, Wl, bias_qkv + (size_t)l * 3 * HH, nullptr, qkv,
            (int)R, 3 * HH, HH, 4, 0.125f);

        band_attn_tiled<<<dim3(NHH, SS / 64, BB), 256, 0, stream>>>(qf, kf, vf, o_bf);
        global_attn_kernel<<<dim3(GG, NHH, BB), 256, 0, stream>>>(qf, kf, vf, o_bf);

        // t1 = o@Wo + bo + x ; x = LN(t1)
        mfma_gemm<<<dim3(HH / 128, R / 128), 256, 0, stream>>>(
            o_bf, Wl + 3 * hh, lbo, x, t1, (int)R, HH, HH, 2, 0.f);
        ln_kernel<<<dim3((int)R), 256, 0, stream>>>(t1, lg1, lb1, x, x_bf);

        // hb = gelu(x@Wf1 + bf1) [bf16]; t1 = hb@Wf2 + bf2 + x ; x = LN(t1)
        mfma_gemm<<<dim3(FF / 128, R / 128), 256, 0, stream>>>(
            x_bf, Wl + 4 * hh, lbf1, nullptr, hb_bf, (int)R, FF, HH, 3, 0.f);
        mfma_gemm<<<dim3(HH / 128, R / 128), 256, 0, stream>>>(
            hb_bf, Wl + 4 * hh + hf, lbf2, x, t1, (int)R, HH, FF, 2, 0.f);
        ln_kernel<<<dim3((int)R), 256, 0, stream>>>(t1, lg2, lb2, x, x_bf);
    }

    pair_head_kernel<<<dim3(BB * PP), 256, 0, stream>>>(x, pair_indices, Wh, bh, (float*)d_out);
}

// Round 4
// 1509.065 us; speedup vs baseline: 6.6257x; 1.4053x over previous
//
#include <hip/hip_runtime.h>
#include <math.h>

#define BB 2
#define SS 2048
#define HH 768
#define NHH 12
#define LL 4
#define DD 64
#define WW 128
#define GG 16
#define PP 128
#define NLL 3
#define FF 3072
#define NCH 8   // key chunks for global-attention flash-decoding split

typedef __bf16 bf16x8 __attribute__((ext_vector_type(8)));
typedef __bf16 bf16x4 __attribute__((ext_vector_type(4)));
typedef float f32x4 __attribute__((ext_vector_type(4)));

// ---------------------------------------------------------------------------
// Embedding gather: x[row,:] = emb[ids[row],:], plus bf16 copy.
__global__ __launch_bounds__(256) void embed_kernel(const int* __restrict__ ids,
    const float* __restrict__ emb, float* __restrict__ x, __bf16* __restrict__ xb)
{
    int row = blockIdx.x;
    int id = ids[row];
    const float* e = emb + (size_t)id * HH;
    float* xp = x + (size_t)row * HH;
    __bf16* xbp = xb + (size_t)row * HH;
    for (int i = threadIdx.x; i < HH; i += 256) {
        float v = e[i];
        xp[i] = v;
        xbp[i] = (__bf16)v;
    }
}

// ---------------------------------------------------------------------------
// Pack per-layer q,k,v biases into [L][3*H]
__global__ __launch_bounds__(256) void pack_bias_kernel(const float* __restrict__ bq,
    const float* __restrict__ bk, const float* __restrict__ bv, float* __restrict__ dst)
{
    int l = blockIdx.x;
    for (int i = threadIdx.x; i < HH; i += 256) {
        dst[(size_t)l * 3 * HH + i]          = bq[(size_t)l * HH + i];
        dst[(size_t)l * 3 * HH + HH + i]     = bk[(size_t)l * HH + i];
        dst[(size_t)l * 3 * HH + 2 * HH + i] = bv[(size_t)l * HH + i];
    }
}

// ---------------------------------------------------------------------------
// Transpose + fp32->bf16: src [K][N] fp32 -> dst [N][K] bf16. blockIdx.z = layer.
__global__ __launch_bounds__(256) void transpose_bf16_kernel(const float* __restrict__ src,
    __bf16* __restrict__ dst, int K, int N, size_t src_ls, size_t dst_ls)
{
    int l = blockIdx.z;
    src += (size_t)l * src_ls;
    dst += (size_t)l * dst_ls;
    __shared__ float t[32][33];
    int tx = threadIdx.x & 31, ty = threadIdx.x >> 5;  // 32 x 8
    int n0 = blockIdx.x * 32, k0 = blockIdx.y * 32;
    for (int i = ty; i < 32; i += 8)
        t[i][tx] = src[(size_t)(k0 + i) * N + n0 + tx];
    __syncthreads();
    for (int i = ty; i < 32; i += 8)
        dst[(size_t)(n0 + i) * K + k0 + tx] = (__bf16)t[tx][i];
}

// ---------------------------------------------------------------------------
// bf16 MFMA GEMM: C[M,N] = epi(A[M,K] @ Bt[N,K]^T + bias)
// 128x128 tile, BK=32, 4 waves (2x2 of 64x64), 16x16x32 MFMA.
// epi: 2 = +res, fp32 out | 3 = gelu, bf16 out | 4 = qkv-split fp32 out
__global__ __launch_bounds__(256) void mfma_gemm(
    const __bf16* __restrict__ A, const __bf16* __restrict__ Bt,
    const float* __restrict__ bias, const float* __restrict__ res,
    void* __restrict__ outv, int M, int N, int K, int epi, float scale)
{
    __shared__ __bf16 As[128 * 32];
    __shared__ __bf16 Bs[128 * 32];
    int tid = threadIdx.x;
    int tileM = blockIdx.y * 128, tileN = blockIdx.x * 128;
    int wave = tid >> 6, lane = tid & 63;
    int wm = (wave >> 1) * 64, wn = (wave & 1) * 64;
    int lr = lane & 15, quad = lane >> 4;

    int s0 = tid, s1 = tid + 256;
    int r0 = s0 >> 2, ko0 = (s0 & 3) * 8;
    int r1 = s1 >> 2, ko1 = (s1 & 3) * 8;
    const __bf16* Ap0 = A + (size_t)(tileM + r0) * K + ko0;
    const __bf16* Ap1 = A + (size_t)(tileM + r1) * K + ko1;
    const __bf16* Bp0 = Bt + (size_t)(tileN + r0) * K + ko0;
    const __bf16* Bp1 = Bt + (size_t)(tileN + r1) * K + ko1;

    f32x4 acc[4][4] = {};

    bf16x8 ra0 = *(const bf16x8*)&Ap0[0];
    bf16x8 ra1 = *(const bf16x8*)&Ap1[0];
    bf16x8 rb0 = *(const bf16x8*)&Bp0[0];
    bf16x8 rb1 = *(const bf16x8*)&Bp1[0];

    for (int k0 = 0; k0 < K; k0 += 32) {
        __syncthreads();
        *(bf16x8*)&As[s0 * 8] = ra0;
        *(bf16x8*)&As[s1 * 8] = ra1;
        *(bf16x8*)&Bs[s0 * 8] = rb0;
        *(bf16x8*)&Bs[s1 * 8] = rb1;
        __syncthreads();
        int kn = k0 + 32;
        if (kn < K) {
            ra0 = *(const bf16x8*)&Ap0[kn];
            ra1 = *(const bf16x8*)&Ap1[kn];
            rb0 = *(const bf16x8*)&Bp0[kn];
            rb1 = *(const bf16x8*)&Bp1[kn];
        }
        bf16x8 af[4], bfr[4];
        #pragma unroll
        for (int i = 0; i < 4; i++) {
            af[i]  = *(const bf16x8*)&As[(wm + i * 16 + lr) * 32 + quad * 8];
            bfr[i] = *(const bf16x8*)&Bs[(wn + i * 16 + lr) * 32 + quad * 8];
        }
        #pragma unroll
        for (int mi = 0; mi < 4; mi++)
            #pragma unroll
            for (int ni = 0; ni < 4; ni++)
                acc[mi][ni] = __builtin_amdgcn_mfma_f32_16x16x32_bf16(
                    af[mi], bfr[ni], acc[mi][ni], 0, 0, 0);
    }

    int zq = (epi == 4) ? tileN / HH : 0;
    #pragma unroll
    for (int mi = 0; mi < 4; mi++) {
        #pragma unroll
        for (int reg = 0; reg < 4; reg++) {
            int row = tileM + wm + mi * 16 + quad * 4 + reg;
            #pragma unroll
            for (int ni = 0; ni < 4; ni++) {
                int col = tileN + wn + ni * 16 + lr;
                float v = acc[mi][ni][reg] + bias[col];
                if (epi == 2) {
                    v += res[(size_t)row * N + col];
                    ((float*)outv)[(size_t)row * N + col] = v;
                } else if (epi == 3) {
                    float t = 0.7978845608028654f * (v + 0.044715f * v * v * v);
                    v = 0.5f * v * (1.0f + tanhf(t));
                    ((__bf16*)outv)[(size_t)row * N + col] = (__bf16)v;
                } else {
                    if (zq == 0) v *= scale;
                    ((float*)outv)[((size_t)zq * M + row) * HH + (col - zq * HH)] = v;
                }
            }
        }
    }
}

// ---------------------------------------------------------------------------
// LayerNorm over H per row; writes fp32 + bf16. Safe for in==out.
__global__ __launch_bounds__(256) void ln_kernel(const float* __restrict__ in,
    const float* __restrict__ g, const float* __restrict__ b,
    float* __restrict__ out, __bf16* __restrict__ outb)
{
    int row = blockIdx.x;
    __shared__ float red[256];
    const float* x = in + (size_t)row * HH;
    int tid = threadIdx.x;
    float s = 0.f;
    for (int i = tid; i < HH; i += 256) s += x[i];
    red[tid] = s; __syncthreads();
    for (int st = 128; st > 0; st >>= 1) { if (tid < st) red[tid] += red[tid + st]; __syncthreads(); }
    float mean = red[0] / HH;
    __syncthreads();
    float vs = 0.f;
    for (int i = tid; i < HH; i += 256) { float d = x[i] - mean; vs += d * d; }
    red[tid] = vs; __syncthreads();
    for (int st = 128; st > 0; st >>= 1) { if (tid < st) red[tid] += red[tid + st]; __syncthreads(); }
    float rstd = rsqrtf(red[0] / HH + 1e-5f);
    __syncthreads();
    for (int i = tid; i < HH; i += 256) {
        float v = (x[i] - mean) * rstd * g[i] + b[i];
        out[(size_t)row * HH + i] = v;
        outb[(size_t)row * HH + i] = (__bf16)v;
    }
}

// ---------------------------------------------------------------------------
// Tiled flash-style band+global-key attention (fp32 math, bf16 output).
__global__ __launch_bounds__(256) void band_attn_tiled(const float* __restrict__ q,
    const float* __restrict__ k, const float* __restrict__ v, __bf16* __restrict__ ob)
{
    __shared__ float Qt[64][64];
    __shared__ float KtPs[64][68];
    __shared__ float Vs[64][68];
    __shared__ float m_sh[64], l_sh[64], alpha_sh[64], mn_sh[64];
    __shared__ float pred[4][64];

    int h  = blockIdx.x;
    int c0 = blockIdx.y * 64;
    int b  = blockIdx.z;
    int tid = threadIdx.x;
    int tx = tid & 15, ty = tid >> 4;

    {
        int r  = tid >> 2;
        int dq = (tid & 3) * 16;
        const float* qp = q + (((size_t)b * SS + c0 + r) * NHH + h) * DD + dq;
        #pragma unroll
        for (int t = 0; t < 16; t++) Qt[dq + t][r] = qp[t];
    }
    if (tid < 64) { m_sh[tid] = -1e30f; l_sh[tid] = 0.f; }

    float O[4][4] = {};

    int lo = c0 - WW; if (lo < GG) lo = GG;
    int hi = c0 + 63 + WW; if (hi > SS - 1) hi = SS - 1;
    int nband = (hi - lo + 1 + 63) / 64;

    for (int t = 0; t <= nband; t++) {
        int kbase = (t == 0) ? 0 : lo + (t - 1) * 64;
        int kend  = (t == 0) ? GG : ((kbase + 64 < hi + 1) ? kbase + 64 : hi + 1);

        __syncthreads();
        {
            int r  = tid >> 2;
            int dq = (tid & 3) * 16;
            int kpos = kbase + r;
            if (kpos < kend) {
                const float* kp = k + (((size_t)b * SS + kpos) * NHH + h) * DD + dq;
                const float* vp = v + (((size_t)b * SS + kpos) * NHH + h) * DD + dq;
                #pragma unroll
                for (int u = 0; u < 16; u++) KtPs[dq + u][r] = kp[u];
                #pragma unroll
                for (int u = 0; u < 4; u++)
                    *(float4*)&Vs[r][dq + 4 * u] = *(const float4*)&vp[4 * u];
            } else {
                #pragma unroll
                for (int u = 0; u < 4; u++)
                    *(float4*)&Vs[r][dq + 4 * u] = make_float4(0.f, 0.f, 0.f, 0.f);
            }
        }
        __syncthreads();

        float Sv[4][4] = {};
        for (int d = 0; d < 64; d++) {
            float4 av = *(const float4*)&Qt[d][ty * 4];
            float4 bv = *(const float4*)&KtPs[d][tx * 4];
            float a_[4] = {av.x, av.y, av.z, av.w};
            float b_[4] = {bv.x, bv.y, bv.z, bv.w};
            #pragma unroll
            for (int i = 0; i < 4; i++)
                #pragma unroll
                for (int j = 0; j < 4; j++) Sv[i][j] += a_[i] * b_[j];
        }
        #pragma unroll
        for (int i = 0; i < 4; i++) {
            int qg = c0 + ty * 4 + i;
            #pragma unroll
            for (int j = 0; j < 4; j++) {
                int kg = kbase + tx * 4 + j;
                bool ok = (kg < kend) &&
                          (t == 0 || (kg - qg <= WW && qg - kg <= WW));
                if (!ok) Sv[i][j] = -1e9f;
            }
        }
        __syncthreads();

        #pragma unroll
        for (int j = 0; j < 4; j++) {
            float4 w = make_float4(Sv[0][j], Sv[1][j], Sv[2][j], Sv[3][j]);
            *(float4*)&KtPs[tx * 4 + j][ty * 4] = w;
        }
        __syncthreads();

        {
            int qq = tid & 63, part = tid >> 6;
            float mx = -1e30f;
            for (int kk = part * 16; kk < part * 16 + 16; kk++)
                mx = fmaxf(mx, KtPs[kk][qq]);
            pred[part][qq] = mx;
        }
        __syncthreads();
        if (tid < 64) {
            float mt = fmaxf(fmaxf(pred[0][tid], pred[1][tid]),
                             fmaxf(pred[2][tid], pred[3][tid]));
            float mo = m_sh[tid];
            float mnew = fmaxf(mo, mt);
            alpha_sh[tid] = __expf(mo - mnew);
            mn_sh[tid] = mnew;
            m_sh[tid] = mnew;
        }
        __syncthreads();
        {
            int qq = tid & 63, part = tid >> 6;
            float mnew = mn_sh[qq];
            float s = 0.f;
            for (int kk = part * 16; kk < part * 16 + 16; kk++) {
                float p = __expf(KtPs[kk][qq] - mnew);
                KtPs[kk][qq] = p;
                s += p;
            }
            pred[part][qq] = s;
        }
        __syncthreads();
        if (tid < 64)
            l_sh[tid] = l_sh[tid] * alpha_sh[tid] +
                        pred[0][tid] + pred[1][tid] + pred[2][tid] + pred[3][tid];

        float al[4];
        #pragma unroll
        for (int i = 0; i < 4; i++) al[i] = alpha_sh[ty * 4 + i];
        #pragma unroll
        for (int i = 0; i < 4; i++)
            #pragma unroll
            for (int j = 0; j < 4; j++) O[i][j] *= al[i];
        for (int kk = 0; kk < 64; kk++) {
            float4 av = *(const float4*)&KtPs[kk][ty * 4];
            float4 bv = *(const float4*)&Vs[kk][tx * 4];
            float a_[4] = {av.x, av.y, av.z, av.w};
            float b_[4] = {bv.x, bv.y, bv.z, bv.w};
            #pragma unroll
            for (int i = 0; i < 4; i++)
                #pragma unroll
                for (int j = 0; j < 4; j++) O[i][j] += a_[i] * b_[j];
        }
    }
    __syncthreads();

    #pragma unroll
    for (int i = 0; i < 4; i++) {
        int qg = c0 + ty * 4 + i;
        float invl = 1.f / l_sh[ty * 4 + i];
        bf16x4 w4;
        w4[0] = (__bf16)(O[i][0] * invl);
        w4[1] = (__bf16)(O[i][1] * invl);
        w4[2] = (__bf16)(O[i][2] * invl);
        w4[3] = (__bf16)(O[i][3] * invl);
        *(bf16x4*)&ob[(((size_t)b * SS + qg) * NHH + h) * DD + tx * 4] = w4;
    }
}

// ---------------------------------------------------------------------------
// Global-query attention pass 1 (flash-decoding split).
// Block = (key chunk ch of 256, head h, batch b); processes all 16 global
// queries against keys [ch*256, ch*256+256) in 4 sub-tiles of 64.
// Writes partial (O[16][64], m[16], l[16]) per (b,h,ch).
#define GP_STRIDE (GG * DD + 2 * GG)
__global__ __launch_bounds__(256) void global_attn_pass1(const float* __restrict__ q,
    const float* __restrict__ k, const float* __restrict__ v, float* __restrict__ part)
{
    __shared__ float Qs[GG][68];
    __shared__ float Kt[64][68];
    __shared__ float Vs[64][68];
    __shared__ float Ssc[64][17];
    __shared__ float m_sh[GG], l_sh[GG], al_sh[GG];

    int ch = blockIdx.x, h = blockIdx.y, b = blockIdx.z;
    int tid = threadIdx.x;
    int q_i = tid >> 4;   // query 0..15
    int g_i = tid & 15;   // group 0..15

    // Load the 16 global Q rows (one float4 per thread)
    {
        const float* qp = q + (((size_t)b * SS + q_i) * NHH + h) * DD + g_i * 4;
        *(float4*)&Qs[q_i][g_i * 4] = *(const float4*)qp;
    }
    if (tid < GG) { m_sh[tid] = -1e30f; l_sh[tid] = 0.f; }

    float O[4] = {0.f, 0.f, 0.f, 0.f};

    for (int t = 0; t < 4; t++) {
        int kbase = ch * 256 + t * 64;
        __syncthreads();
        {
            int r = tid >> 2, dq = (tid & 3) * 16;
            const float* kp = k + (((size_t)b * SS + kbase + r) * NHH + h) * DD + dq;
            const float* vp = v + (((size_t)b * SS + kbase + r) * NHH + h) * DD + dq;
            #pragma unroll
            for (int u = 0; u < 16; u++) Kt[dq + u][r] = kp[u];
            #pragma unroll
            for (int u = 0; u < 4; u++)
                *(float4*)&Vs[r][dq + 4 * u] = *(const float4*)&vp[4 * u];
        }
        __syncthreads();

        // scores: thread (q_i, g_i) -> keys g_i*4 .. g_i*4+3
        float sc[4] = {0.f, 0.f, 0.f, 0.f};
        for (int d = 0; d < 64; d++) {
            float qv = Qs[q_i][d];
            #pragma unroll
            for (int j = 0; j < 4; j++) sc[j] += qv * Kt[d][g_i * 4 + j];
        }
        #pragma unroll
        for (int j = 0; j < 4; j++) Ssc[g_i * 4 + j][q_i] = sc[j];
        __syncthreads();

        // online softmax update per query (16 threads)
        if (tid < GG) {
            float mo = m_sh[tid], mx = mo;
            for (int kk = 0; kk < 64; kk++) mx = fmaxf(mx, Ssc[kk][tid]);
            float al = __expf(mo - mx);
            al_sh[tid] = al; m_sh[tid] = mx;
            float s = 0.f;
            for (int kk = 0; kk < 64; kk++) {
                float p = __expf(Ssc[kk][tid] - mx);
                Ssc[kk][tid] = p;
                s += p;
            }
            l_sh[tid] = l_sh[tid] * al + s;
        }
        __syncthreads();

        // PV: thread (q_i, g_i) accumulates dims g_i*4 .. +3
        float al = al_sh[q_i];
        #pragma unroll
        for (int j = 0; j < 4; j++) O[j] *= al;
        for (int kk = 0; kk < 64; kk++) {
            float p = Ssc[kk][q_i];
            #pragma unroll
            for (int j = 0; j < 4; j++) O[j] += p * Vs[kk][g_i * 4 + j];
        }
    }
    __syncthreads();

    size_t base = (((size_t)b * NHH + h) * NCH + ch) * GP_STRIDE;
    #pragma unroll
    for (int j = 0; j < 4; j++) part[base + q_i * DD + g_i * 4 + j] = O[j];
    if (tid < GG) {
        part[base + GG * DD + tid] = m_sh[tid];
        part[base + GG * DD + GG + tid] = l_sh[tid];
    }
}

// ---------------------------------------------------------------------------
// Global-query attention pass 2: merge NCH chunk partials, write bf16 rows.
__global__ __launch_bounds__(64) void global_attn_combine(const float* __restrict__ part,
    __bf16* __restrict__ ob)
{
    int g = blockIdx.x, h = blockIdx.y, b = blockIdx.z;
    int d = threadIdx.x;
    size_t base0 = (((size_t)b * NHH + h) * NCH) * GP_STRIDE;
    float m[NCH], l[NCH], M = -1e30f;
    #pragma unroll
    for (int ch = 0; ch < NCH; ch++) {
        m[ch] = part[base0 + ch * GP_STRIDE + GG * DD + g];
        l[ch] = part[base0 + ch * GP_STRIDE + GG * DD + GG + g];
        M = fmaxf(M, m[ch]);
    }
    float L = 0.f, o = 0.f;
    #pragma unroll
    for (int ch = 0; ch < NCH; ch++) {
        float w = __expf(m[ch] - M);
        L += w * l[ch];
        o += w * part[base0 + ch * GP_STRIDE + g * DD + d];
    }
    ob[(((size_t)b * SS + g) * NHH + h) * DD + d] = (__bf16)(o / L);
}

// ---------------------------------------------------------------------------
// Pair head: out[row,:] = concat(x[b,i,:], x[b,j,:]) @ Wh + bh
__global__ __launch_bounds__(256) void pair_head_kernel(const float* __restrict__ x,
    const int* __restrict__ pairs, const float* __restrict__ Wh,
    const float* __restrict__ bh, float* __restrict__ out)
{
    int row = blockIdx.x;
    int b = row / PP;
    int i = pairs[row * 2 + 0];
    int j = pairs[row * 2 + 1];
    const float* xi = x + ((size_t)b * SS + i) * HH;
    const float* xj = x + ((size_t)b * SS + j) * HH;
    float acc[NLL] = {};
    for (int e = threadIdx.x; e < 2 * HH; e += 256) {
        float val = (e < HH) ? xi[e] : xj[e - HH];
        #pragma unroll
        for (int c = 0; c < NLL; c++) acc[c] += val * Wh[e * NLL + c];
    }
    __shared__ float red[NLL * 256];
    #pragma unroll
    for (int c = 0; c < NLL; c++) red[c * 256 + threadIdx.x] = acc[c];
    __syncthreads();
    for (int st = 128; st > 0; st >>= 1) {
        if (threadIdx.x < st)
            #pragma unroll
            for (int c = 0; c < NLL; c++)
                red[c * 256 + threadIdx.x] += red[c * 256 + threadIdx.x + st];
        __syncthreads();
    }
    if (threadIdx.x < NLL) out[row * NLL + threadIdx.x] = red[threadIdx.x * 256] + bh[threadIdx.x];
}

// ---------------------------------------------------------------------------
extern "C" void kernel_launch(void* const* d_in, const int* in_sizes, int n_in,
                              void* d_out, int out_size, void* d_ws, size_t ws_size,
                              hipStream_t stream)
{
    const int*   input_ids    = (const int*)d_in[0];
    const int*   pair_indices = (const int*)d_in[1];
    const float* emb   = (const float*)d_in[2];
    const float* Wq    = (const float*)d_in[3];
    const float* bq    = (const float*)d_in[4];
    const float* Wk    = (const float*)d_in[5];
    const float* bk    = (const float*)d_in[6];
    const float* Wv    = (const float*)d_in[7];
    const float* bv    = (const float*)d_in[8];
    const float* Wo    = (const float*)d_in[9];
    const float* bo    = (const float*)d_in[10];
    const float* ln1_g = (const float*)d_in[11];
    const float* ln1_b = (const float*)d_in[12];
    const float* Wf1   = (const float*)d_in[13];
    const float* bf1   = (const float*)d_in[14];
    const float* Wf2   = (const float*)d_in[15];
    const float* bf2   = (const float*)d_in[16];
    const float* ln2_g = (const float*)d_in[17];
    const float* ln2_b = (const float*)d_in[18];
    const float* Wh    = (const float*)d_in[19];
    const float* bh    = (const float*)d_in[20];

    const size_t R = (size_t)BB * SS;
    const size_t LWS = 4 * (size_t)HH * HH + 2 * (size_t)HH * FF;

    char* w = (char*)d_ws;
    float* x      = (float*)w;  w += R * HH * 4;
    float* t1     = (float*)w;  w += R * HH * 4;
    float* qkv    = (float*)w;  w += 3 * R * HH * 4;
    __bf16* x_bf  = (__bf16*)w; w += R * HH * 2;
    __bf16* o_bf  = (__bf16*)w; w += R * HH * 2;
    float* bias_qkv = (float*)w; w += LL * 3 * HH * 4;
    float* gpart  = (float*)w;  w += (size_t)BB * NHH * NCH * GP_STRIDE * 4;
    __bf16* Wbf   = (__bf16*)w; w += LL * LWS * 2;
    __bf16* hb_bf = (__bf16*)qkv;
    float* qf = qkv;
    float* kf = qkv + R * HH;
    float* vf = qkv + 2 * R * HH;

    pack_bias_kernel<<<dim3(LL), 256, 0, stream>>>(bq, bk, bv, bias_qkv);
    size_t hh = (size_t)HH * HH, hf = (size_t)HH * FF;
    transpose_bf16_kernel<<<dim3(HH/32, HH/32, LL), 256, 0, stream>>>(Wq, Wbf,            HH, HH, hh, LWS);
    transpose_bf16_kernel<<<dim3(HH/32, HH/32, LL), 256, 0, stream>>>(Wk, Wbf + hh,       HH, HH, hh, LWS);
    transpose_bf16_kernel<<<dim3(HH/32, HH/32, LL), 256, 0, stream>>>(Wv, Wbf + 2 * hh,   HH, HH, hh, LWS);
    transpose_bf16_kernel<<<dim3(HH/32, HH/32, LL), 256, 0, stream>>>(Wo, Wbf + 3 * hh,   HH, HH, hh, LWS);
    transpose_bf16_kernel<<<dim3(FF/32, HH/32, LL), 256, 0, stream>>>(Wf1, Wbf + 4 * hh,  HH, FF, hf, LWS);
    transpose_bf16_kernel<<<dim3(HH/32, FF/32, LL), 256, 0, stream>>>(Wf2, Wbf + 4 * hh + hf, FF, HH, hf, LWS);

    embed_kernel<<<dim3((int)R), 256, 0, stream>>>(input_ids, emb, x, x_bf);

    for (int l = 0; l < LL; l++) {
        __bf16* Wl = Wbf + (size_t)l * LWS;
        const float* lbo  = bo  + (size_t)l * HH;
        const float* lg1  = ln1_g + (size_t)l * HH;  const float* lb1 = ln1_b + (size_t)l * HH;
        const float* lbf1 = bf1 + (size_t)l * FF;
        const float* lbf2 = bf2 + (size_t)l * HH;
        const float* lg2  = ln2_g + (size_t)l * HH;  const float* lb2 = ln2_b + (size_t)l * HH;

        mfma_gemm<<<dim3(3 * HH / 128, R / 128), 256, 0, stream>>>(
            x_bf, Wl, bias_qkv + (size_t)l * 3 * HH, nullptr, qkv,
            (int)R, 3 * HH, HH, 4, 0.125f);

        band_attn_tiled<<<dim3(NHH, SS / 64, BB), 256, 0, stream>>>(qf, kf, vf, o_bf);
        global_attn_pass1<<<dim3(NCH, NHH, BB), 256, 0, stream>>>(qf, kf, vf, gpart);
        global_attn_combine<<<dim3(GG, NHH, BB), 64, 0, stream>>>(gpart, o_bf);

        mfma_gemm<<<dim3(HH / 128, R / 128), 256, 0, stream>>>(
            o_bf, Wl + 3 * hh, lbo, x, t1, (int)R, HH, HH, 2, 0.f);
        ln_kernel<<<dim3((int)R), 256, 0, stream>>>(t1, lg1, lb1, x, x_bf);

        mfma_gemm<<<dim3(FF / 128, R / 128), 256, 0, stream>>>(
            x_bf, Wl + 4 * hh, lbf1, nullptr, hb_bf, (int)R, FF, HH, 3, 0.f);
        mfma_gemm<<<dim3(HH / 128, R / 128), 256, 0, stream>>>(
            hb_bf, Wl + 4 * hh + hf, lbf2, x, t1, (int)R, HH, FF, 2, 0.f);
        ln_kernel<<<dim3((int)R), 256, 0, stream>>>(t1, lg2, lb2, x, x_bf);
    }

    pair_head_kernel<<<dim3(BB * PP), 256, 0, stream>>>(x, pair_indices, Wh, bh, (float*)d_out);
}